// Round 9
// baseline (127.483 us; speedup 1.0000x reference)
//
#include <hip/hip_runtime.h>

#define NN    1024
#define INF   21
#define EE    128
#define NB    65   // 2*BINS+1
#define BINSV 32
#define TI    32
#define TJ    32

typedef float f32x4 __attribute__((ext_vector_type(4)));

// Kernel 1 (merged prep): blocks [0, NN) do the two linear projections;
// blocks [NN, NN+NB) build ptab[d][e] = Wp[e][d] + bp[e].
__global__ __launch_bounds__(128) void prep_kernel(
    const float* __restrict__ tf,
    const float* __restrict__ Wa, const float* __restrict__ ba,
    const float* __restrict__ Wb, const float* __restrict__ bb,
    const float* __restrict__ Wp, const float* __restrict__ bp,
    float* __restrict__ a, float* __restrict__ b, float* __restrict__ ptab) {
  const int e = threadIdx.x;  // 0..127
  if (blockIdx.x < NN) {
    const int i = blockIdx.x;
    __shared__ float row[INF];
    if (e < INF) row[e] = tf[i * INF + e];
    __syncthreads();
    float sa = ba[e];
    float sb = bb[e];
#pragma unroll
    for (int k = 0; k < INF; ++k) {
      float r = row[k];
      sa = fmaf(r, Wa[e * INF + k], sa);
      sb = fmaf(r, Wb[e * INF + k], sb);
    }
    a[i * EE + e] = sa;
    b[i * EE + e] = sb;
  } else {
    const int d = blockIdx.x - NN;  // 0..64
    ptab[d * EE + e] = Wp[e * NB + d] + bp[e];
  }
}

// Kernel 2: 32x32 output tile per block, 256 threads (4 waves) -> 8 blocks/CU
// = full occupancy. Per block the read working set (a-tile 16KB + b-tile 16KB
// + hot p rows) is L1-RESIDENT: L2 read traffic drops 512MB -> ~35MB.
// Each wave holds its 4 b-row-pairs in REGISTERS across the whole i-loop.
// Stores: 1KB contiguous per wave, 16KB contiguous per (block, i).
__global__ __launch_bounds__(256, 8) void fill_kernel(
    const float* __restrict__ a, const float* __restrict__ b,
    const float* __restrict__ ptab, const int* __restrict__ ri,
    float* __restrict__ out) {
  __shared__ int sri[NN];
  const int tid = threadIdx.x;
  for (int t = tid; t < NN; t += 256) sri[t] = ri[t];
  __syncthreads();

  const int lane = tid & 63;
  const int hi   = lane >> 5;        // which j of the wave's pair
  const int e4   = lane & 31;        // f32x4 index within E
  const int wv   = tid >> 6;         // wave 0..3
  const int i0   = blockIdx.y * TI;
  const int j0   = blockIdx.x * TJ;

  const f32x4* __restrict__ a4 = reinterpret_cast<const f32x4*>(a);
  const f32x4* __restrict__ b4 = reinterpret_cast<const f32x4*>(b);
  const f32x4* __restrict__ p4 = reinterpret_cast<const f32x4*>(ptab);

  // Hoist this wave's 4 b-row-pairs (jj = 0..3) into registers.
  int   jr[4];
  f32x4 bv[4];
  int   rj[4];
#pragma unroll
  for (int jj = 0; jj < 4; ++jj) {
    jr[jj] = j0 + jj * 8 + wv * 2 + hi;
    bv[jj] = b4[jr[jj] * 32 + e4];
    rj[jj] = sri[jr[jj]];
  }

  f32x4* __restrict__ o4 = reinterpret_cast<f32x4*>(out);

  for (int ii = 0; ii < TI; ++ii) {
    const int i = i0 + ii;
    const f32x4 av = a4[i * 32 + e4];
    const int rii = sri[i];
    const size_t orow = (size_t)i * NN;
#pragma unroll
    for (int jj = 0; jj < 4; ++jj) {
      int d = rii - rj[jj];
      d = min(max(d, -BINSV), BINSV) + BINSV;
      const f32x4 o = av + bv[jj] + p4[d * 32 + e4];
      __builtin_nontemporal_store(o, o4 + (orow + jr[jj]) * 32 + e4);
    }
  }
}

extern "C" void kernel_launch(void* const* d_in, const int* in_sizes, int n_in,
                              void* d_out, int out_size, void* d_ws, size_t ws_size,
                              hipStream_t stream) {
  const float* tf = (const float*)d_in[0];
  const int*   ri = (const int*)d_in[1];
  const float* Wa = (const float*)d_in[2];
  const float* ba = (const float*)d_in[3];
  const float* Wb = (const float*)d_in[4];
  const float* bb = (const float*)d_in[5];
  const float* Wp = (const float*)d_in[6];
  const float* bp = (const float*)d_in[7];
  float* out = (float*)d_out;

  float* ws   = (float*)d_ws;
  float* a    = ws;                 // N*E floats
  float* b    = ws + NN * EE;       // N*E floats
  float* ptab = ws + 2 * NN * EE;   // 65*E floats

  prep_kernel<<<NN + NB, 128, 0, stream>>>(tf, Wa, ba, Wb, bb, Wp, bp, a, b, ptab);
  dim3 grid(NN / TJ, NN / TI);
  fill_kernel<<<grid, 256, 0, stream>>>(a, b, ptab, ri, out);
}

// Round 10
// 106.437 us; speedup vs baseline: 1.1977x; 1.1977x over previous
//
#include <hip/hip_runtime.h>

#define NN    1024
#define INF   21
#define EE    128
#define NB    65   // 2*BINS+1
#define BINSV 32

typedef float f32x4 __attribute__((ext_vector_type(4)));

// Kernel 1 (merged prep): blocks [0, NN) do the two linear projections;
// blocks [NN, NN+NB) build ptab[d][e] = Wp[e][d] + bp[e].
__global__ __launch_bounds__(128) void prep_kernel(
    const float* __restrict__ tf,
    const float* __restrict__ Wa, const float* __restrict__ ba,
    const float* __restrict__ Wb, const float* __restrict__ bb,
    const float* __restrict__ Wp, const float* __restrict__ bp,
    float* __restrict__ a, float* __restrict__ b, float* __restrict__ ptab) {
  const int e = threadIdx.x;  // 0..127
  if (blockIdx.x < NN) {
    const int i = blockIdx.x;
    __shared__ float row[INF];
    if (e < INF) row[e] = tf[i * INF + e];
    __syncthreads();
    float sa = ba[e];
    float sb = bb[e];
#pragma unroll
    for (int k = 0; k < INF; ++k) {
      float r = row[k];
      sa = fmaf(r, Wa[e * INF + k], sa);
      sb = fmaf(r, Wb[e * INF + k], sb);
    }
    a[i * EE + e] = sa;
    b[i * EE + e] = sb;
  } else {
    const int d = blockIdx.x - NN;  // 0..64
    ptab[d * EE + e] = Wp[e * NB + d] + bp[e];
  }
}

// Kernel 2: R3 shape (1024 blocks x 512 thr, block = row i, full occupancy)
// but each wave owns a PRIVATE CONTIGUOUS 64 KB span of the row:
// wave wv -> j in [128*wv, 128*wv+128), storing 1 KB per iter marching
// LINEARLY (+1 KB). Device-wide: 8192 pure linear write streams (memset-like
// per-channel pattern) instead of 8 KB-strided interleaves. 2-deep pipeline,
// nontemporal stores. b-loads 1 KB contiguous; p rows L1/L2-hot.
__global__ __launch_bounds__(512) void fill_kernel(
    const float* __restrict__ a, const float* __restrict__ b,
    const float* __restrict__ ptab, const int* __restrict__ ri,
    float* __restrict__ out) {
  __shared__ int sri[NN];
  const int tid = threadIdx.x;
  for (int t = tid; t < NN; t += 512) sri[t] = ri[t];
  __syncthreads();

  const int lane = tid & 63;
  const int hi   = lane >> 5;        // j parity within the 1 KB pair
  const int e4   = lane & 31;        // f32x4 index within E
  const int wv   = tid >> 6;         // wave 0..7
  const int i    = blockIdx.x;
  const int jb   = wv << 7;          // wave's j-span base (128 j's = 64 KB)

  const f32x4* __restrict__ b4 = reinterpret_cast<const f32x4*>(b);
  const f32x4* __restrict__ p4 = reinterpret_cast<const f32x4*>(ptab);

  const f32x4 av = reinterpret_cast<const f32x4*>(a + i * EE)[e4];
  const int rii = sri[i];

  // wave's linear store cursor (f32x4 units); iter t stores at +t*64
  f32x4* __restrict__ o4 = reinterpret_cast<f32x4*>(out) +
      ((size_t)i * NN + jb) * 32 + hi * 32 + e4;

  auto dbin = [&](int j) {
    int d = rii - sri[j];
    return min(max(d, -BINSV), BINSV) + BINSV;
  };

  // 2-deep software pipeline over t = 0..63 (j = jb + 2t + hi)
  int jA = jb + hi;
  f32x4 bv0 = b4[jA * 32 + e4];
  f32x4 pv0 = p4[dbin(jA) * 32 + e4];
  int jB = jb + 2 + hi;
  f32x4 bv1 = b4[jB * 32 + e4];
  f32x4 pv1 = p4[dbin(jB) * 32 + e4];

  for (int t = 0; t < 64; t += 2) {
    const int jn0 = jb + ((2 * t + 4) & 127) + hi;   // masked tail prefetch
    const f32x4 nb0 = b4[jn0 * 32 + e4];
    const f32x4 np0 = p4[dbin(jn0) * 32 + e4];
    __builtin_nontemporal_store(av + bv0 + pv0, o4 + (size_t)t * 64);
    const int jn1 = jb + ((2 * t + 6) & 127) + hi;
    const f32x4 nb1 = b4[jn1 * 32 + e4];
    const f32x4 np1 = p4[dbin(jn1) * 32 + e4];
    __builtin_nontemporal_store(av + bv1 + pv1, o4 + (size_t)(t + 1) * 64);
    bv0 = nb0; pv0 = np0;
    bv1 = nb1; pv1 = np1;
  }
}

extern "C" void kernel_launch(void* const* d_in, const int* in_sizes, int n_in,
                              void* d_out, int out_size, void* d_ws, size_t ws_size,
                              hipStream_t stream) {
  const float* tf = (const float*)d_in[0];
  const int*   ri = (const int*)d_in[1];
  const float* Wa = (const float*)d_in[2];
  const float* ba = (const float*)d_in[3];
  const float* Wb = (const float*)d_in[4];
  const float* bb = (const float*)d_in[5];
  const float* Wp = (const float*)d_in[6];
  const float* bp = (const float*)d_in[7];
  float* out = (float*)d_out;

  float* ws   = (float*)d_ws;
  float* a    = ws;                 // N*E floats
  float* b    = ws + NN * EE;       // N*E floats
  float* ptab = ws + 2 * NN * EE;   // 65*E floats

  prep_kernel<<<NN + NB, 128, 0, stream>>>(tf, Wa, ba, Wb, bb, Wp, bp, a, b, ptab);
  fill_kernel<<<NN, 512, 0, stream>>>(a, b, ptab, ri, out);
}